// Round 21
// baseline (348.250 us; speedup 1.0000x reference)
//
#include <hip/hip_runtime.h>
#include <stdint.h>

typedef __attribute__((ext_vector_type(8))) short bf16x8;
typedef __attribute__((ext_vector_type(8))) _Float16 f16x8;
typedef __attribute__((ext_vector_type(4))) float f32x4;
typedef __attribute__((ext_vector_type(4))) unsigned short us4;
typedef unsigned short u16;

#define DEVI static __device__ __forceinline__

#define Bb 4
#define Tt 4096
#define Cch 512
#define DFFd 2048
#define Mrows (Bb*Tt)
#define TRI 8650752ull   // u16 elements per packed causal pane = PANE(32)

DEVI u16 f2bf(float f){
  union{float f;unsigned u;} v; v.f = f;
  unsigned r = v.u + 0x7FFFu + ((v.u >> 16) & 1u);
  return (u16)(r >> 16);
}
DEVI u16 f2h(float f){
  union{_Float16 h; u16 u;} v; v.h = (_Float16)f; return v.u;
}
DEVI float h2f(u16 h){
  union{u16 u; _Float16 h;} v; v.u = h; return (float)v.h;
}
// packed-triangular pane offset (u16 elements): sum_{j<q}(j+1)*128*128
DEVI size_t PANE(int q){ return (size_t)8192 * (size_t)(q*(q+1)); }

DEVI void gload16(const void* g, void* l){
  __builtin_amdgcn_global_load_lds((const __attribute__((address_space(1))) unsigned int*)g,
                                   (__attribute__((address_space(3))) unsigned int*)l, 16, 0, 0);
}

// Bank-conflict-free swizzle (both-sides involution), verified round 16 (conflicts -> 0):
#define RDSWZ(l15, l4) (((l4)*16) ^ ((((l15) >> 1) & 3) << 4))
#define SRCSWZ(lane) ((((lane) & 3)*8) ^ ((((lane) >> 3) & 3) << 3))

// ---- 8-wave stagers (512-thread kernels) ----
DEVI void stage256x64_w8(const u16* __restrict__ base, int ld, char* lds, int w, int lane){
  #pragma unroll
  for(int i = 0; i < 4; i++){
    int s = i & 1;
    int chunk = w + (i >> 1)*8;              // 0..15
    int row = chunk*16 + (lane >> 2);
    int col = s*32 + SRCSWZ(lane);
    gload16(base + (size_t)row * ld + col, lds + s*16384 + chunk*1024 + lane*16);
  }
}
DEVI void stage128x64_w8(const u16* __restrict__ base, int ld, char* lds, int w, int lane){
  #pragma unroll
  for(int i = 0; i < 2; i++){
    int s = i;
    int row = w*16 + (lane >> 2);
    int col = s*32 + SRCSWZ(lane);
    gload16(base + (size_t)row * ld + col, lds + s*8192 + w*1024 + lane*16);
  }
}
// ---- 16-wave stager (1024-thread kernels): 256x64 tile, 2 k-subtiles of [256][32] ----
DEVI void stage256x64_w16(const u16* __restrict__ base, int ld, char* lds, int w, int lane){
  #pragma unroll
  for(int i = 0; i < 2; i++){
    int s = i;
    int row = w*16 + (lane >> 2);
    int col = s*32 + SRCSWZ(lane);
    gload16(base + (size_t)row * ld + col, lds + s*16384 + w*1024 + lane*16);
  }
}

// ---------------- cast f32 -> f16 ----------------
__global__ void k_cast_f16(const float* __restrict__ in, u16* __restrict__ out, int n){
  int i = (blockIdx.x * blockDim.x + threadIdx.x) * 4;
  if(i < n){
    float4 f = *(const float4*)(in + i);
    us4 o; o.x = f2h(f.x); o.y = f2h(f.y); o.z = f2h(f.z); o.w = f2h(f.w);
    *(us4*)(out + i) = o;
  }
}

// ------------- transpose-cast f32 -> f16 -------------
__global__ void k_transpose_f32_f16(const float* __restrict__ in, u16* __restrict__ out,
                                    int inStride, int outStride){
  __shared__ float tile[32][33];
  int c0 = blockIdx.x * 32, r0 = blockIdx.y * 32;
  int tx = threadIdx.x, ty = threadIdx.y; // (32,8)
  #pragma unroll
  for(int j = 0; j < 4; j++)
    tile[ty + 8*j][tx] = in[(size_t)(r0 + ty + 8*j) * inStride + c0 + tx];
  __syncthreads();
  #pragma unroll
  for(int j = 0; j < 4; j++)
    out[(size_t)(c0 + ty + 8*j) * outStride + r0 + tx] = f2h(tile[tx][ty + 8*j]);
}

// ------------- transpose-cast f32 -> bf16 -------------
__global__ void k_transpose_f32_bf16(const float* __restrict__ in, u16* __restrict__ out,
                                     int inStride, int outStride){
  __shared__ float tile[32][33];
  int c0 = blockIdx.x * 32, r0 = blockIdx.y * 32;
  int tx = threadIdx.x, ty = threadIdx.y;
  #pragma unroll
  for(int j = 0; j < 4; j++)
    tile[ty + 8*j][tx] = in[(size_t)(r0 + ty + 8*j) * inStride + c0 + tx];
  __syncthreads();
  #pragma unroll
  for(int j = 0; j < 4; j++)
    out[(size_t)(c0 + ty + 8*j) * outStride + r0 + tx] = f2bf(tile[tx][ty + 8*j]);
}

// ---------------- f16 GEMM core, BM=256 BN=128 BK=64, 512 threads ----------------
DEVI void core_f16_256(const u16* __restrict__ A, const u16* __restrict__ B,
                       int lda, int ldb, int K, u16* As, u16* Bs, f32x4 (&acc)[4][4]){
  const int t = threadIdx.x;
  const int lane = t & 63, w = t >> 6;     // w 0..7
  const int l15 = lane & 15, l4 = lane >> 4;
  const int wr = (w >> 1) * 64, wc = (w & 1) * 64;
  const int ro = RDSWZ(l15, l4);
  for(int kt = 0; kt < K; kt += 64){
    __syncthreads();
    stage256x64_w8(A + kt, lda, (char*)As, w, lane);
    stage128x64_w8(B + kt, ldb, (char*)Bs, w, lane);
    __syncthreads();
    f16x8 af[2][4], bfr[2][4];
    #pragma unroll
    for(int s = 0; s < 2; s++){
      #pragma unroll
      for(int mi = 0; mi < 4; mi++)
        af[s][mi] = *(const f16x8*)((const char*)As + s*16384 + (wr + mi*16 + l15)*64 + ro);
      #pragma unroll
      for(int ni = 0; ni < 4; ni++)
        bfr[s][ni] = *(const f16x8*)((const char*)Bs + s*8192 + (wc + ni*16 + l15)*64 + ro);
    }
    #pragma unroll
    for(int s = 0; s < 2; s++)
      #pragma unroll
      for(int mi = 0; mi < 4; mi++)
        #pragma unroll
        for(int ni = 0; ni < 4; ni++)
          acc[mi][ni] = __builtin_amdgcn_mfma_f32_16x16x32_f16(af[s][mi], bfr[s][ni], acc[mi][ni], 0, 0, 0);
  }
}

// ---------------- f16 GEMM core, BM=256 BN=256 BK=64, 1024 threads / 16 waves ----------------
DEVI void core_f16_1k(const u16* __restrict__ A, const u16* __restrict__ B,
                      int lda, int ldb, int K, u16* As, u16* Bs, f32x4 (&acc)[4][4]){
  const int t = threadIdx.x;
  const int lane = t & 63, w = t >> 6;     // w 0..15
  const int l15 = lane & 15, l4 = lane >> 4;
  const int wr = (w >> 2) * 64, wc = (w & 3) * 64;
  const int ro = RDSWZ(l15, l4);
  for(int kt = 0; kt < K; kt += 64){
    __syncthreads();
    stage256x64_w16(A + kt, lda, (char*)As, w, lane);
    stage256x64_w16(B + kt, ldb, (char*)Bs, w, lane);
    __syncthreads();
    f16x8 af[2][4], bfr[2][4];
    #pragma unroll
    for(int s = 0; s < 2; s++){
      #pragma unroll
      for(int mi = 0; mi < 4; mi++)
        af[s][mi] = *(const f16x8*)((const char*)As + s*16384 + (wr + mi*16 + l15)*64 + ro);
      #pragma unroll
      for(int ni = 0; ni < 4; ni++)
        bfr[s][ni] = *(const f16x8*)((const char*)Bs + s*16384 + (wc + ni*16 + l15)*64 + ro);
    }
    #pragma unroll
    for(int s = 0; s < 2; s++)
      #pragma unroll
      for(int mi = 0; mi < 4; mi++)
        #pragma unroll
        for(int ni = 0; ni < 4; ni++)
          acc[mi][ni] = __builtin_amdgcn_mfma_f32_16x16x32_f16(af[s][mi], bfr[s][ni], acc[mi][ni], 0, 0, 0);
  }
}

// ---------------- bf16 GEMM core, BM=256 BN=256 BK=64, 1024 threads / 16 waves ----------------
DEVI void core_bf16_1k(const u16* __restrict__ A, const u16* __restrict__ B,
                       int lda, int ldb, int K, u16* As, u16* Bs, f32x4 (&acc)[4][4]){
  const int t = threadIdx.x;
  const int lane = t & 63, w = t >> 6;
  const int l15 = lane & 15, l4 = lane >> 4;
  const int wr = (w >> 2) * 64, wc = (w & 3) * 64;
  const int ro = RDSWZ(l15, l4);
  for(int kt = 0; kt < K; kt += 64){
    __syncthreads();
    stage256x64_w16(A + kt, lda, (char*)As, w, lane);
    stage256x64_w16(B + kt, ldb, (char*)Bs, w, lane);
    __syncthreads();
    bf16x8 af[2][4], bfr[2][4];
    #pragma unroll
    for(int s = 0; s < 2; s++){
      #pragma unroll
      for(int mi = 0; mi < 4; mi++)
        af[s][mi] = *(const bf16x8*)((const char*)As + s*16384 + (wr + mi*16 + l15)*64 + ro);
      #pragma unroll
      for(int ni = 0; ni < 4; ni++)
        bfr[s][ni] = *(const bf16x8*)((const char*)Bs + s*16384 + (wc + ni*16 + l15)*64 + ro);
    }
    #pragma unroll
    for(int s = 0; s < 2; s++)
      #pragma unroll
      for(int mi = 0; mi < 4; mi++)
        #pragma unroll
        for(int ni = 0; ni < 4; ni++)
          acc[mi][ni] = __builtin_amdgcn_mfma_f32_16x16x32_bf16(af[s][mi], bfr[s][ni], acc[mi][ni], 0, 0, 0);
  }
}

// ---------------- fused QKV projection (f16, BM=256, BN=128): cols<1024 -> QK, else blocked Vg ----------------
__global__ __launch_bounds__(512) void k_qkv(const u16* __restrict__ Xf,
                                             const u16* __restrict__ Wt,
                                             u16* __restrict__ QK,
                                             u16* __restrict__ Vg){
  __shared__ u16 As[16384], Bs[8192];
  const int bm = blockIdx.x * 256, bn = blockIdx.y * 128;
  f32x4 acc[4][4] = {};
  core_f16_256(Xf + (size_t)bm*512, Wt + (size_t)bn*512, 512, 512, 512, As, Bs, acc);
  const int t = threadIdx.x, lane = t & 63, w = t >> 6;
  const int l15 = lane & 15, l4 = lane >> 4;
  const int wr = (w >> 1) * 64, wc = (w & 1) * 64;
  #pragma unroll
  for(int mi = 0; mi < 4; mi++)
    #pragma unroll
    for(int ni = 0; ni < 4; ni++){
      int col = bn + wc + ni*16 + l15;
      #pragma unroll
      for(int r = 0; r < 4; r++){
        int row = bm + wr + mi*16 + l4*4 + r;
        u16 h = f2h(acc[mi][ni][r]);
        if(col < 1024){
          QK[(size_t)row * 1024 + col] = h;
        } else {
          int c = col - 1024;
          int b = row >> 12, tq = row & 4095;
          Vg[(size_t)b*Cch*Tt + ((size_t)(tq >> 5) * 512 + c) * 32 + (tq & 31)] = h;
        }
      }
    }
}

// ---------------- causal score GEMM (BM=256, BN=256 kt-pair): grid (16,16,nb); qy descending ----------------
__global__ __launch_bounds__(1024) void k_score(const u16* __restrict__ QK, int b0,
                                                u16* __restrict__ Sp){
  const int kp = blockIdx.x, qy = 15 - blockIdx.y;
  if(kp > qy) return;
  const int zb = blockIdx.z;
  const u16* QKb = QK + (size_t)(b0 + zb) * Tt * 1024;
  u16* Spz = Sp + (size_t)zb * TRI;
  __shared__ u16 As[16384], Bs[16384];
  const u16* A = QKb + (size_t)(qy*256) * 1024;        // q rows (256)
  const u16* B = QKb + (size_t)(kp*256) * 1024 + 512;  // k rows (256)
  f32x4 acc[4][4] = {};
  core_f16_1k(A, B, 1024, 1024, 512, As, Bs, acc);
  const int t = threadIdx.x, lane = t & 63, w = t >> 6;
  const int l15 = lane & 15, l4 = lane >> 4;
  const int wr = (w >> 2) * 64, wc = (w & 3) * 64;
  const int qt_row = qy*2 + (wr >> 7);     // wave-uniform pane index
  const int ldc = (qt_row + 1) * 128;
  const int rof = wr & 64;
  u16* C = Spz + PANE(qt_row);
  #pragma unroll
  for(int mi = 0; mi < 4; mi++)
    #pragma unroll
    for(int ni = 0; ni < 4; ni++){
      int csub = wc + ni*16;               // 0..240, lane-uniform
      int kt_tile = kp*2 + (csub >> 7);
      if(kt_tile > qt_row) continue;       // fully-masked sub-tile: skip store
      int colin = (csub & 127) + l15;      // column within pane tile
      const bool diag = (kt_tile == qt_row);
      #pragma unroll
      for(int r = 0; r < 4; r++){
        int rl = rof + mi*16 + l4*4 + r;   // row within pane (0..127)
        float v = acc[mi][ni][r];
        if(diag && colin > rl) v = -__builtin_inff();
        C[(size_t)rl * ldc + kt_tile*128 + colin] = f2h(v);
      }
    }
}

// ---------------- softmax: wave per row; f16 S -> normalized f16 P in place ----------------
__global__ __launch_bounds__(256) void k_softmax(u16* __restrict__ Sp){
  u16* Spz = Sp + (size_t)blockIdx.z * TRI;
  const int w = threadIdx.x >> 6, lane = threadIdx.x & 63;
  const int r = (1023 - blockIdx.x) * 4 + w;  // 0..4095, descending qt
  const int qt = r >> 7;
  const int nc = qt + 1;                      // chunks of 128 u16 (ushort2/lane)
  const int L = nc * 128;
  const size_t base = PANE(qt) + (size_t)(r & 127) * L;
  ushort2* rp = (ushort2*)(Spz + base);
  float2 v[32];
  float mx = -__builtin_inff();
  #pragma unroll
  for(int c = 0; c < 32; c++) if(c < nc){
    ushort2 h = rp[c*64 + lane];
    v[c].x = h2f(h.x); v[c].y = h2f(h.y);
    mx = fmaxf(mx, fmaxf(v[c].x, v[c].y));
  }
  #pragma unroll
  for(int s = 1; s < 64; s <<= 1) mx = fmaxf(mx, __shfl_xor(mx, s));
  float sm = 0.f;
  #pragma unroll
  for(int c = 0; c < 32; c++) if(c < nc){
    v[c].x = __expf(v[c].x - mx);
    v[c].y = __expf(v[c].y - mx);
    sm += v[c].x + v[c].y;
  }
  #pragma unroll
  for(int s = 1; s < 64; s <<= 1) sm += __shfl_xor(sm, s);
  const float inv = 1.f / sm;
  #pragma unroll
  for(int c = 0; c < 32; c++) if(c < nc){
    ushort2 o; o.x = f2h(v[c].x * inv); o.y = f2h(v[c].y * inv);
    rp[c*64 + lane] = o;
  }
}

// ---------------- PV GEMM (f16, BM=128, BN=128, BK=64, 512 thr / 8 waves, no atomics) ----------------
__global__ __launch_bounds__(512) void k_pv(const u16* __restrict__ Pp, const u16* __restrict__ Vg,
                                            u16* __restrict__ NV, int b0){
  const int nc = blockIdx.x, qt = 31 - blockIdx.y, zb = blockIdx.z;
  const int L = (qt + 1) * 128;
  __shared__ u16 As[8192], Bs[8192];
  const u16* A = Pp + (size_t)zb * TRI + PANE(qt);             // f16 P, row stride L
  const u16* Vgb = Vg + (size_t)(b0 + zb) * Cch * Tt;          // blocked [t/32][512 c][32] f16
  const int t = threadIdx.x, lane = t & 63, w = t >> 6;        // w 0..7
  const int l15 = lane & 15, l4 = lane >> 4;
  const int wr = (w >> 1) * 32, wc = (w & 1) * 64;             // wave tile 32x64
  const int ro = RDSWZ(l15, l4);
  f32x4 acc[2][4] = {};
  for(int kt = 0; kt < L; kt += 64){
    __syncthreads();
    stage128x64_w8(A + kt, L, (char*)As, w, lane);
    // B: blocked Vg, 2 subtiles of 8KB; 8 waves x 1KB each
    const size_t kvb0 = (size_t)(kt >> 5) * 16384 + nc*4096;   // u16 elems
    #pragma unroll
    for(int i = 0; i < 2; i++){
      int s = i;
      int crow = w*16 + (lane >> 2);
      int kvo = SRCSWZ(lane);
      gload16(Vgb + kvb0 + (size_t)s*16384 + (size_t)crow*32 + kvo,
              (char*)Bs + s*8192 + w*1024 + lane*16);
    }
    __syncthreads();
    f16x8 af[2][2], bfr[2][4];
    #pragma unroll
    for(int s = 0; s < 2; s++){
      #pragma unroll
      for(int mi = 0; mi < 2; mi++)
        af[s][mi] = *(const f16x8*)((const char*)As + s*8192 + (wr + mi*16 + l15)*64 + ro);
      #pragma unroll
      for(int ni = 0; ni < 4; ni++)
        bfr[s][ni] = *(const f16x8*)((const char*)Bs + s*8192 + (wc + ni*16 + l15)*64 + ro);
    }
    #pragma unroll
    for(int s = 0; s < 2; s++)
      #pragma unroll
      for(int mi = 0; mi < 2; mi++)
        #pragma unroll
        for(int ni = 0; ni < 4; ni++)
          acc[mi][ni] = __builtin_amdgcn_mfma_f32_16x16x32_f16(af[s][mi], bfr[s][ni], acc[mi][ni], 0, 0, 0);
  }
  u16* Cb = NV + ((size_t)(b0 + zb) * Tt + qt*128) * Cch + nc*128;
  #pragma unroll
  for(int mi = 0; mi < 2; mi++)
    #pragma unroll
    for(int ni = 0; ni < 4; ni++){
      int cl = wc + ni*16 + l15;
      #pragma unroll
      for(int r = 0; r < 4; r++){
        int rl = wr + mi*16 + l4*4 + r;
        Cb[(size_t)rl * Cch + cl] = f2bf(acc[mi][ni][r]);
      }
    }
}

// ---------------- FFN1 (BM=256, BN=256, 1024 thr): +bias, relu, bf16 out ----------------
__global__ __launch_bounds__(1024) void k_ffn1(const u16* __restrict__ A,
                                               const u16* __restrict__ Bt,
                                               u16* __restrict__ Hout,
                                               const float* __restrict__ bias){
  __shared__ u16 As[16384], Bs[16384];
  const int bm = blockIdx.x * 256, bn = blockIdx.y * 256;
  f32x4 acc[4][4] = {};
  core_bf16_1k(A + (size_t)bm*512, Bt + (size_t)bn*512, 512, 512, 512, As, Bs, acc);
  const int t = threadIdx.x, lane = t & 63, w = t >> 6;
  const int l15 = lane & 15, l4 = lane >> 4;
  const int wr = (w >> 2) * 64, wc = (w & 3) * 64;
  #pragma unroll
  for(int mi = 0; mi < 4; mi++)
    #pragma unroll
    for(int ni = 0; ni < 4; ni++){
      int col = bn + wc + ni*16 + l15;
      float bv = bias[col];
      #pragma unroll
      for(int r = 0; r < 4; r++){
        int row = bm + wr + mi*16 + l4*4 + r;
        float v = acc[mi][ni][r] + bv;
        v = v > 0.f ? v : 0.f;
        Hout[(size_t)row * DFFd + col] = f2bf(v);
      }
    }
}

// ---------------- FFN2 (BM=128, BN=128, BK=64, 512 thr / 8 waves): +bias, f32 direct store ----------------
__global__ __launch_bounds__(512) void k_ffn2(const u16* __restrict__ A,
                                              const u16* __restrict__ Bt,
                                              float* __restrict__ out,
                                              const float* __restrict__ bias){
  __shared__ u16 As[8192], Bs[8192];
  const int bn = blockIdx.x * 128, bm = blockIdx.y * 128;
  const int t = threadIdx.x, lane = t & 63, w = t >> 6;        // w 0..7
  const int l15 = lane & 15, l4 = lane >> 4;
  const int wr = (w >> 1) * 32, wc = (w & 1) * 64;             // wave tile 32x64
  const int ro = RDSWZ(l15, l4);
  const u16* Ap = A + (size_t)bm*2048;
  const u16* Bp = Bt + (size_t)bn*2048;
  f32x4 acc[2][4] = {};
  for(int kt = 0; kt < 2048; kt += 64){
    __syncthreads();
    stage128x64_w8(Ap + kt, 2048, (char*)As, w, lane);
    stage128x64_w8(Bp + kt, 2048, (char*)Bs, w, lane);
    __syncthreads();
    bf16x8 af[2][2], bfr[2][4];
    #pragma unroll
    for(int s = 0; s < 2; s++){
      #pragma unroll
      for(int mi = 0; mi < 2; mi++)
        af[s][mi] = *(const bf16x8*)((const char*)As + s*8192 + (wr + mi*16 + l15)*64 + ro);
      #pragma unroll
      for(int ni = 0; ni < 4; ni++)
        bfr[s][ni] = *(const bf16x8*)((const char*)Bs + s*8192 + (wc + ni*16 + l15)*64 + ro);
    }
    #pragma unroll
    for(int s = 0; s < 2; s++)
      #pragma unroll
      for(int mi = 0; mi < 2; mi++)
        #pragma unroll
        for(int ni = 0; ni < 4; ni++)
          acc[mi][ni] = __builtin_amdgcn_mfma_f32_16x16x32_bf16(af[s][mi], bfr[s][ni], acc[mi][ni], 0, 0, 0);
  }
  #pragma unroll
  for(int mi = 0; mi < 2; mi++)
    #pragma unroll
    for(int ni = 0; ni < 4; ni++){
      int col = bn + wc + ni*16 + l15;
      float bv = bias[col];
      #pragma unroll
      for(int r = 0; r < 4; r++){
        int row = bm + wr + mi*16 + l4*4 + r;
        out[(size_t)row * Cch + col] = acc[mi][ni][r] + bv;
      }
    }
}

// ---------------- launch ----------------
extern "C" void kernel_launch(void* const* d_in, const int* in_sizes, int n_in,
                              void* d_out, int out_size, void* d_ws, size_t ws_size,
                              hipStream_t stream){
  (void)in_sizes; (void)n_in; (void)out_size;
  const float* X  = (const float*)d_in[0];
  const float* Wq = (const float*)d_in[1];
  const float* Wk = (const float*)d_in[2];
  const float* Wv = (const float*)d_in[3];
  const float* W1 = (const float*)d_in[4];
  const float* b1 = (const float*)d_in[5];
  const float* W2 = (const float*)d_in[6];
  const float* b2 = (const float*)d_in[7];
  float* out = (float*)d_out;

  const size_t MB = 1024ull*1024ull;
  const size_t PANE_B = (size_t)TRI * 2;   // 17,301,504 B
  char* ws = (char*)d_ws;

  int nb = 1;
  if(ws_size >= 4*PANE_B + 71*MB) nb = 4;
  else if(ws_size >= 2*PANE_B + 71*MB) nb = 2;

  u16*   Sp = (u16*)ws;
  u16*   Xf = (u16*)ws;
  u16*   H  = (u16*)ws;
  size_t off = (size_t)nb * PANE_B;
  u16*   QK   = (u16*)(ws + off);  off += 32*MB;
  u16*   Vg   = (u16*)(ws + off);  off += 16*MB;
  u16*   NV   = (u16*)(ws + off);  off += 16*MB;
  u16*   Wt   = (u16*)(ws + off);  off += 2*MB;   // [1536][512] f16 (1.5M used)
  u16*   W1t  = (u16*)(ws + off);  off += 2*MB;
  u16*   W2t  = (u16*)(ws + off);

  dim3 tb(32, 8);

  // 1. cast X -> f16
  k_cast_f16<<<Mrows*Cch/4/256, 256, 0, stream>>>(X, Xf, Mrows*Cch);

  // 2. weight transposes: Wq/Wk/Wv -> f16 Wt rows; W1/W2 -> bf16
  k_transpose_f32_f16<<<dim3(16,16), tb, 0, stream>>>(Wq, Wt,            512, 512);
  k_transpose_f32_f16<<<dim3(16,16), tb, 0, stream>>>(Wk, Wt +  512*512, 512, 512);
  k_transpose_f32_f16<<<dim3(16,16), tb, 0, stream>>>(Wv, Wt + 1024*512, 512, 512);
  k_transpose_f32_bf16<<<dim3(64,16), tb, 0, stream>>>(W1, W1t, 2048, 512);
  k_transpose_f32_bf16<<<dim3(16,64), tb, 0, stream>>>(W2, W2t, 512, 2048);

  // 3. fused QKV projection (f16, BM=256, BN=128)
  k_qkv<<<dim3(64, 12), 512, 0, stream>>>(Xf, Wt, QK, Vg);

  // 4. attention: nb batches per pass (longest-first), f16 S/P
  for(int b0 = 0; b0 < Bb; b0 += nb){
    k_score<<<dim3(16, 16, nb), 1024, 0, stream>>>(QK, b0, Sp);
    k_softmax<<<dim3(1024, 1, nb), 256, 0, stream>>>(Sp);
    k_pv<<<dim3(4, 32, nb), 512, 0, stream>>>(Sp, Vg, NV, b0);
  }

  // 5. FFN (FFN1 256x256 16-wave; FFN2 8-wave 128x128)
  k_ffn1<<<dim3(64, 8), 1024, 0, stream>>>(NV, W1t, H, b1);
  k_ffn2<<<dim3(4, 128), 512, 0, stream>>>(H, W2t, out, b2);
}

// Round 22
// 325.323 us; speedup vs baseline: 1.0705x; 1.0705x over previous
//
#include <hip/hip_runtime.h>
#include <stdint.h>

typedef __attribute__((ext_vector_type(8))) short bf16x8;
typedef __attribute__((ext_vector_type(8))) _Float16 f16x8;
typedef __attribute__((ext_vector_type(4))) float f32x4;
typedef __attribute__((ext_vector_type(4))) unsigned short us4;
typedef unsigned short u16;

#define DEVI static __device__ __forceinline__

#define Bb 4
#define Tt 4096
#define Cch 512
#define DFFd 2048
#define Mrows (Bb*Tt)
#define TRI 8650752ull   // u16 elements per packed causal pane = PANE(32)

DEVI u16 f2bf(float f){
  union{float f;unsigned u;} v; v.f = f;
  unsigned r = v.u + 0x7FFFu + ((v.u >> 16) & 1u);
  return (u16)(r >> 16);
}
DEVI u16 f2h(float f){
  union{_Float16 h; u16 u;} v; v.h = (_Float16)f; return v.u;
}
DEVI float h2f(u16 h){
  union{u16 u; _Float16 h;} v; v.u = h; return (float)v.h;
}
// packed-triangular pane offset (u16 elements): sum_{j<q}(j+1)*128*128
DEVI size_t PANE(int q){ return (size_t)8192 * (size_t)(q*(q+1)); }

DEVI void gload16(const void* g, void* l){
  __builtin_amdgcn_global_load_lds((const __attribute__((address_space(1))) unsigned int*)g,
                                   (__attribute__((address_space(3))) unsigned int*)l, 16, 0, 0);
}

// Bank-conflict-free swizzle (both-sides involution), verified round 16 (conflicts -> 0):
#define RDSWZ(l15, l4) (((l4)*16) ^ ((((l15) >> 1) & 3) << 4))
#define SRCSWZ(lane) ((((lane) & 3)*8) ^ ((((lane) >> 3) & 3) << 3))

// ---- 8-wave stagers (512-thread kernels) ----
DEVI void stage256x64_w8(const u16* __restrict__ base, int ld, char* lds, int w, int lane){
  #pragma unroll
  for(int i = 0; i < 4; i++){
    int s = i & 1;
    int chunk = w + (i >> 1)*8;              // 0..15
    int row = chunk*16 + (lane >> 2);
    int col = s*32 + SRCSWZ(lane);
    gload16(base + (size_t)row * ld + col, lds + s*16384 + chunk*1024 + lane*16);
  }
}
DEVI void stage128x64_w8(const u16* __restrict__ base, int ld, char* lds, int w, int lane){
  #pragma unroll
  for(int i = 0; i < 2; i++){
    int s = i;
    int row = w*16 + (lane >> 2);
    int col = s*32 + SRCSWZ(lane);
    gload16(base + (size_t)row * ld + col, lds + s*8192 + w*1024 + lane*16);
  }
}

// ---------------- cast f32 -> f16 ----------------
__global__ void k_cast_f16(const float* __restrict__ in, u16* __restrict__ out, int n){
  int i = (blockIdx.x * blockDim.x + threadIdx.x) * 4;
  if(i < n){
    float4 f = *(const float4*)(in + i);
    us4 o; o.x = f2h(f.x); o.y = f2h(f.y); o.z = f2h(f.z); o.w = f2h(f.w);
    *(us4*)(out + i) = o;
  }
}

// ------------- transpose-cast f32 -> f16 -------------
__global__ void k_transpose_f32_f16(const float* __restrict__ in, u16* __restrict__ out,
                                    int inStride, int outStride){
  __shared__ float tile[32][33];
  int c0 = blockIdx.x * 32, r0 = blockIdx.y * 32;
  int tx = threadIdx.x, ty = threadIdx.y; // (32,8)
  #pragma unroll
  for(int j = 0; j < 4; j++)
    tile[ty + 8*j][tx] = in[(size_t)(r0 + ty + 8*j) * inStride + c0 + tx];
  __syncthreads();
  #pragma unroll
  for(int j = 0; j < 4; j++)
    out[(size_t)(c0 + ty + 8*j) * outStride + r0 + tx] = f2h(tile[tx][ty + 8*j]);
}

// ------------- transpose-cast f32 -> bf16 -------------
__global__ void k_transpose_f32_bf16(const float* __restrict__ in, u16* __restrict__ out,
                                     int inStride, int outStride){
  __shared__ float tile[32][33];
  int c0 = blockIdx.x * 32, r0 = blockIdx.y * 32;
  int tx = threadIdx.x, ty = threadIdx.y;
  #pragma unroll
  for(int j = 0; j < 4; j++)
    tile[ty + 8*j][tx] = in[(size_t)(r0 + ty + 8*j) * inStride + c0 + tx];
  __syncthreads();
  #pragma unroll
  for(int j = 0; j < 4; j++)
    out[(size_t)(c0 + ty + 8*j) * outStride + r0 + tx] = f2bf(tile[tx][ty + 8*j]);
}

// ---------------- f16 GEMM core, BM=256 BN=128 BK=64, 512 threads ----------------
DEVI void core_f16_256(const u16* __restrict__ A, const u16* __restrict__ B,
                       int lda, int ldb, int K, u16* As, u16* Bs, f32x4 (&acc)[4][4]){
  const int t = threadIdx.x;
  const int lane = t & 63, w = t >> 6;     // w 0..7
  const int l15 = lane & 15, l4 = lane >> 4;
  const int wr = (w >> 1) * 64, wc = (w & 1) * 64;
  const int ro = RDSWZ(l15, l4);
  for(int kt = 0; kt < K; kt += 64){
    __syncthreads();
    stage256x64_w8(A + kt, lda, (char*)As, w, lane);
    stage128x64_w8(B + kt, ldb, (char*)Bs, w, lane);
    __syncthreads();
    f16x8 af[2][4], bfr[2][4];
    #pragma unroll
    for(int s = 0; s < 2; s++){
      #pragma unroll
      for(int mi = 0; mi < 4; mi++)
        af[s][mi] = *(const f16x8*)((const char*)As + s*16384 + (wr + mi*16 + l15)*64 + ro);
      #pragma unroll
      for(int ni = 0; ni < 4; ni++)
        bfr[s][ni] = *(const f16x8*)((const char*)Bs + s*8192 + (wc + ni*16 + l15)*64 + ro);
    }
    #pragma unroll
    for(int s = 0; s < 2; s++)
      #pragma unroll
      for(int mi = 0; mi < 4; mi++)
        #pragma unroll
        for(int ni = 0; ni < 4; ni++)
          acc[mi][ni] = __builtin_amdgcn_mfma_f32_16x16x32_f16(af[s][mi], bfr[s][ni], acc[mi][ni], 0, 0, 0);
  }
}

// ---------------- bf16 GEMM core, BM=256 BN=128 BK=64, 512 threads ----------------
DEVI void core_bf16_256(const u16* __restrict__ A, const u16* __restrict__ B,
                        int lda, int ldb, int K, u16* As, u16* Bs, f32x4 (&acc)[4][4]){
  const int t = threadIdx.x;
  const int lane = t & 63, w = t >> 6;
  const int l15 = lane & 15, l4 = lane >> 4;
  const int wr = (w >> 1) * 64, wc = (w & 1) * 64;
  const int ro = RDSWZ(l15, l4);
  for(int kt = 0; kt < K; kt += 64){
    __syncthreads();
    stage256x64_w8(A + kt, lda, (char*)As, w, lane);
    stage128x64_w8(B + kt, ldb, (char*)Bs, w, lane);
    __syncthreads();
    bf16x8 af[2][4], bfr[2][4];
    #pragma unroll
    for(int s = 0; s < 2; s++){
      #pragma unroll
      for(int mi = 0; mi < 4; mi++)
        af[s][mi] = *(const bf16x8*)((const char*)As + s*16384 + (wr + mi*16 + l15)*64 + ro);
      #pragma unroll
      for(int ni = 0; ni < 4; ni++)
        bfr[s][ni] = *(const bf16x8*)((const char*)Bs + s*8192 + (wc + ni*16 + l15)*64 + ro);
    }
    #pragma unroll
    for(int s = 0; s < 2; s++)
      #pragma unroll
      for(int mi = 0; mi < 4; mi++)
        #pragma unroll
        for(int ni = 0; ni < 4; ni++)
          acc[mi][ni] = __builtin_amdgcn_mfma_f32_16x16x32_bf16(af[s][mi], bfr[s][ni], acc[mi][ni], 0, 0, 0);
  }
}

// ---------------- fused QKV projection (f16, BM=256): cols<1024 -> QK, cols>=1024 -> blocked Vg ----------------
__global__ __launch_bounds__(512) void k_qkv(const u16* __restrict__ Xf,
                                             const u16* __restrict__ Wt,
                                             u16* __restrict__ QK,
                                             u16* __restrict__ Vg){
  __shared__ u16 As[16384], Bs[8192];
  const int bm = blockIdx.x * 256, bn = blockIdx.y * 128;
  f32x4 acc[4][4] = {};
  core_f16_256(Xf + (size_t)bm*512, Wt + (size_t)bn*512, 512, 512, 512, As, Bs, acc);
  const int t = threadIdx.x, lane = t & 63, w = t >> 6;
  const int l15 = lane & 15, l4 = lane >> 4;
  const int wr = (w >> 1) * 64, wc = (w & 1) * 64;
  #pragma unroll
  for(int mi = 0; mi < 4; mi++)
    #pragma unroll
    for(int ni = 0; ni < 4; ni++){
      int col = bn + wc + ni*16 + l15;
      #pragma unroll
      for(int r = 0; r < 4; r++){
        int row = bm + wr + mi*16 + l4*4 + r;
        u16 h = f2h(acc[mi][ni][r]);
        if(col < 1024){
          QK[(size_t)row * 1024 + col] = h;
        } else {
          int c = col - 1024;
          int b = row >> 12, tq = row & 4095;
          Vg[(size_t)b*Cch*Tt + ((size_t)(tq >> 5) * 512 + c) * 32 + (tq & 31)] = h;
        }
      }
    }
}

// ---------------- causal score GEMM (BM=256): grid (32,16,nb); qy descending ----------------
__global__ __launch_bounds__(512) void k_score(const u16* __restrict__ QK, int b0,
                                               u16* __restrict__ Sp){
  const int kt = blockIdx.x, qy = 15 - blockIdx.y;
  if(kt > 2*qy + 1) return;
  const int zb = blockIdx.z;
  const u16* QKb = QK + (size_t)(b0 + zb) * Tt * 1024;
  u16* Spz = Sp + (size_t)zb * TRI;
  __shared__ u16 As[16384], Bs[8192];
  const u16* A = QKb + (size_t)(qy*256) * 1024;        // q rows (256)
  const u16* B = QKb + (size_t)(kt*128) * 1024 + 512;  // k rows (128)
  f32x4 acc[4][4] = {};
  core_f16_256(A, B, 1024, 1024, 512, As, Bs, acc);
  const int t = threadIdx.x, lane = t & 63, w = t >> 6;
  const int l15 = lane & 15, l4 = lane >> 4;
  const int wr = (w >> 1) * 64, wc = (w & 1) * 64;
  const int qt_row = qy*2 + (wr >> 7);     // wave-uniform pane index
  if(kt > qt_row) return;                  // fully-masked upper half: no stores
  const int ldc = (qt_row + 1) * 128;
  const int rof = wr & 64;
  u16* C = Spz + PANE(qt_row) + (size_t)kt*128;
  const bool diag = (kt == qt_row);
  #pragma unroll
  for(int mi = 0; mi < 4; mi++)
    #pragma unroll
    for(int ni = 0; ni < 4; ni++){
      int cl = wc + ni*16 + l15;
      #pragma unroll
      for(int r = 0; r < 4; r++){
        int rl = rof + mi*16 + l4*4 + r;   // row within pane (0..127)
        float v = acc[mi][ni][r];
        if(diag && cl > rl) v = -__builtin_inff();
        C[(size_t)rl * ldc + cl] = f2h(v);
      }
    }
}

// ---------------- softmax: wave per row; f16 S -> normalized f16 P in place ----------------
__global__ __launch_bounds__(256) void k_softmax(u16* __restrict__ Sp){
  u16* Spz = Sp + (size_t)blockIdx.z * TRI;
  const int w = threadIdx.x >> 6, lane = threadIdx.x & 63;
  const int r = (1023 - blockIdx.x) * 4 + w;  // 0..4095, descending qt
  const int qt = r >> 7;
  const int nc = qt + 1;                      // chunks of 128 u16 (ushort2/lane)
  const int L = nc * 128;
  const size_t base = PANE(qt) + (size_t)(r & 127) * L;
  ushort2* rp = (ushort2*)(Spz + base);
  float2 v[32];
  float mx = -__builtin_inff();
  #pragma unroll
  for(int c = 0; c < 32; c++) if(c < nc){
    ushort2 h = rp[c*64 + lane];
    v[c].x = h2f(h.x); v[c].y = h2f(h.y);
    mx = fmaxf(mx, fmaxf(v[c].x, v[c].y));
  }
  #pragma unroll
  for(int s = 1; s < 64; s <<= 1) mx = fmaxf(mx, __shfl_xor(mx, s));
  float sm = 0.f;
  #pragma unroll
  for(int c = 0; c < 32; c++) if(c < nc){
    v[c].x = __expf(v[c].x - mx);
    v[c].y = __expf(v[c].y - mx);
    sm += v[c].x + v[c].y;
  }
  #pragma unroll
  for(int s = 1; s < 64; s <<= 1) sm += __shfl_xor(sm, s);
  const float inv = 1.f / sm;
  #pragma unroll
  for(int c = 0; c < 32; c++) if(c < nc){
    ushort2 o; o.x = f2h(v[c].x * inv); o.y = f2h(v[c].y * inv);
    rp[c*64 + lane] = o;
  }
}

// ---------------- PV GEMM (f16, BM=128, BN=128, BK=64, 512 thr / 8 waves, no atomics) ----------------
__global__ __launch_bounds__(512) void k_pv(const u16* __restrict__ Pp, const u16* __restrict__ Vg,
                                            u16* __restrict__ NV, int b0){
  const int nc = blockIdx.x, qt = 31 - blockIdx.y, zb = blockIdx.z;
  const int L = (qt + 1) * 128;
  __shared__ u16 As[8192], Bs[8192];
  const u16* A = Pp + (size_t)zb * TRI + PANE(qt);             // f16 P, row stride L
  const u16* Vgb = Vg + (size_t)(b0 + zb) * Cch * Tt;          // blocked [t/32][512 c][32] f16
  const int t = threadIdx.x, lane = t & 63, w = t >> 6;        // w 0..7
  const int l15 = lane & 15, l4 = lane >> 4;
  const int wr = (w >> 1) * 32, wc = (w & 1) * 64;             // wave tile 32x64
  const int ro = RDSWZ(l15, l4);
  f32x4 acc[2][4] = {};
  for(int kt = 0; kt < L; kt += 64){
    __syncthreads();
    stage128x64_w8(A + kt, L, (char*)As, w, lane);
    // B: blocked Vg, 2 subtiles of 8KB; 8 waves x 1KB each
    const size_t kvb0 = (size_t)(kt >> 5) * 16384 + nc*4096;   // u16 elems
    #pragma unroll
    for(int i = 0; i < 2; i++){
      int s = i;
      int crow = w*16 + (lane >> 2);
      int kvo = SRCSWZ(lane);
      gload16(Vgb + kvb0 + (size_t)s*16384 + (size_t)crow*32 + kvo,
              (char*)Bs + s*8192 + w*1024 + lane*16);
    }
    __syncthreads();
    f16x8 af[2][2], bfr[2][4];
    #pragma unroll
    for(int s = 0; s < 2; s++){
      #pragma unroll
      for(int mi = 0; mi < 2; mi++)
        af[s][mi] = *(const f16x8*)((const char*)As + s*8192 + (wr + mi*16 + l15)*64 + ro);
      #pragma unroll
      for(int ni = 0; ni < 4; ni++)
        bfr[s][ni] = *(const f16x8*)((const char*)Bs + s*8192 + (wc + ni*16 + l15)*64 + ro);
    }
    #pragma unroll
    for(int s = 0; s < 2; s++)
      #pragma unroll
      for(int mi = 0; mi < 2; mi++)
        #pragma unroll
        for(int ni = 0; ni < 4; ni++)
          acc[mi][ni] = __builtin_amdgcn_mfma_f32_16x16x32_f16(af[s][mi], bfr[s][ni], acc[mi][ni], 0, 0, 0);
  }
  u16* Cb = NV + ((size_t)(b0 + zb) * Tt + qt*128) * Cch + nc*128;
  #pragma unroll
  for(int mi = 0; mi < 2; mi++)
    #pragma unroll
    for(int ni = 0; ni < 4; ni++){
      int cl = wc + ni*16 + l15;
      #pragma unroll
      for(int r = 0; r < 4; r++){
        int rl = wr + mi*16 + l4*4 + r;
        Cb[(size_t)rl * Cch + cl] = f2bf(acc[mi][ni][r]);
      }
    }
}

// ---------------- FFN1 (BM=256): +bias, relu, bf16 out ----------------
__global__ __launch_bounds__(512) void k_ffn1(const u16* __restrict__ A,
                                              const u16* __restrict__ Bt,
                                              u16* __restrict__ Hout,
                                              const float* __restrict__ bias){
  __shared__ u16 As[16384], Bs[8192];
  const int bm = blockIdx.x * 256, bn = blockIdx.y * 128;
  f32x4 acc[4][4] = {};
  core_bf16_256(A + (size_t)bm*512, Bt + (size_t)bn*512, 512, 512, 512, As, Bs, acc);
  const int t = threadIdx.x, lane = t & 63, w = t >> 6;
  const int l15 = lane & 15, l4 = lane >> 4;
  const int wr = (w >> 1) * 64, wc = (w & 1) * 64;
  #pragma unroll
  for(int mi = 0; mi < 4; mi++)
    #pragma unroll
    for(int ni = 0; ni < 4; ni++){
      int col = bn + wc + ni*16 + l15;
      float bv = bias[col];
      #pragma unroll
      for(int r = 0; r < 4; r++){
        int row = bm + wr + mi*16 + l4*4 + r;
        float v = acc[mi][ni][r] + bv;
        v = v > 0.f ? v : 0.f;
        Hout[(size_t)row * DFFd + col] = f2bf(v);
      }
    }
}

// ---------------- FFN2 (BM=128, BN=128, BK=64, 512 thr / 8 waves): +bias, f32 direct store ----------------
__global__ __launch_bounds__(512) void k_ffn2(const u16* __restrict__ A,
                                              const u16* __restrict__ Bt,
                                              float* __restrict__ out,
                                              const float* __restrict__ bias){
  __shared__ u16 As[8192], Bs[8192];
  const int bn = blockIdx.x * 128, bm = blockIdx.y * 128;
  const int t = threadIdx.x, lane = t & 63, w = t >> 6;        // w 0..7
  const int l15 = lane & 15, l4 = lane >> 4;
  const int wr = (w >> 1) * 32, wc = (w & 1) * 64;             // wave tile 32x64
  const int ro = RDSWZ(l15, l4);
  const u16* Ap = A + (size_t)bm*2048;
  const u16* Bp = Bt + (size_t)bn*2048;
  f32x4 acc[2][4] = {};
  for(int kt = 0; kt < 2048; kt += 64){
    __syncthreads();
    stage128x64_w8(Ap + kt, 2048, (char*)As, w, lane);
    stage128x64_w8(Bp + kt, 2048, (char*)Bs, w, lane);
    __syncthreads();
    bf16x8 af[2][2], bfr[2][4];
    #pragma unroll
    for(int s = 0; s < 2; s++){
      #pragma unroll
      for(int mi = 0; mi < 2; mi++)
        af[s][mi] = *(const bf16x8*)((const char*)As + s*8192 + (wr + mi*16 + l15)*64 + ro);
      #pragma unroll
      for(int ni = 0; ni < 4; ni++)
        bfr[s][ni] = *(const bf16x8*)((const char*)Bs + s*8192 + (wc + ni*16 + l15)*64 + ro);
    }
    #pragma unroll
    for(int s = 0; s < 2; s++)
      #pragma unroll
      for(int mi = 0; mi < 2; mi++)
        #pragma unroll
        for(int ni = 0; ni < 4; ni++)
          acc[mi][ni] = __builtin_amdgcn_mfma_f32_16x16x32_bf16(af[s][mi], bfr[s][ni], acc[mi][ni], 0, 0, 0);
  }
  #pragma unroll
  for(int mi = 0; mi < 2; mi++)
    #pragma unroll
    for(int ni = 0; ni < 4; ni++){
      int col = bn + wc + ni*16 + l15;
      float bv = bias[col];
      #pragma unroll
      for(int r = 0; r < 4; r++){
        int row = bm + wr + mi*16 + l4*4 + r;
        out[(size_t)row * Cch + col] = acc[mi][ni][r] + bv;
      }
    }
}

// ---------------- launch ----------------
extern "C" void kernel_launch(void* const* d_in, const int* in_sizes, int n_in,
                              void* d_out, int out_size, void* d_ws, size_t ws_size,
                              hipStream_t stream){
  (void)in_sizes; (void)n_in; (void)out_size;
  const float* X  = (const float*)d_in[0];
  const float* Wq = (const float*)d_in[1];
  const float* Wk = (const float*)d_in[2];
  const float* Wv = (const float*)d_in[3];
  const float* W1 = (const float*)d_in[4];
  const float* b1 = (const float*)d_in[5];
  const float* W2 = (const float*)d_in[6];
  const float* b2 = (const float*)d_in[7];
  float* out = (float*)d_out;

  const size_t MB = 1024ull*1024ull;
  const size_t PANE_B = (size_t)TRI * 2;   // 17,301,504 B
  char* ws = (char*)d_ws;

  int nb = 1;
  if(ws_size >= 4*PANE_B + 71*MB) nb = 4;
  else if(ws_size >= 2*PANE_B + 71*MB) nb = 2;

  u16*   Sp = (u16*)ws;
  u16*   Xf = (u16*)ws;
  u16*   H  = (u16*)ws;
  size_t off = (size_t)nb * PANE_B;
  u16*   QK   = (u16*)(ws + off);  off += 32*MB;
  u16*   Vg   = (u16*)(ws + off);  off += 16*MB;
  u16*   NV   = (u16*)(ws + off);  off += 16*MB;
  u16*   Wt   = (u16*)(ws + off);  off += 2*MB;   // [1536][512] f16 (1.5M used)
  u16*   W1t  = (u16*)(ws + off);  off += 2*MB;
  u16*   W2t  = (u16*)(ws + off);

  dim3 tb(32, 8);

  // 1. cast X -> f16
  k_cast_f16<<<Mrows*Cch/4/256, 256, 0, stream>>>(X, Xf, Mrows*Cch);

  // 2. weight transposes: Wq/Wk/Wv -> f16 Wt rows; W1/W2 -> bf16
  k_transpose_f32_f16<<<dim3(16,16), tb, 0, stream>>>(Wq, Wt,            512, 512);
  k_transpose_f32_f16<<<dim3(16,16), tb, 0, stream>>>(Wk, Wt +  512*512, 512, 512);
  k_transpose_f32_f16<<<dim3(16,16), tb, 0, stream>>>(Wv, Wt + 1024*512, 512, 512);
  k_transpose_f32_bf16<<<dim3(64,16), tb, 0, stream>>>(W1, W1t, 2048, 512);
  k_transpose_f32_bf16<<<dim3(16,64), tb, 0, stream>>>(W2, W2t, 512, 2048);

  // 3. fused QKV projection (f16, BM=256)
  k_qkv<<<dim3(64, 12), 512, 0, stream>>>(Xf, Wt, QK, Vg);

  // 4. attention: nb batches per pass (longest-first), f16 S/P
  for(int b0 = 0; b0 < Bb; b0 += nb){
    k_score<<<dim3(32, 16, nb), 512, 0, stream>>>(QK, b0, Sp);
    k_softmax<<<dim3(1024, 1, nb), 256, 0, stream>>>(Sp);
    k_pv<<<dim3(4, 32, nb), 512, 0, stream>>>(Sp, Vg, NV, b0);
  }

  // 5. FFN (FFN1 BM=256; FFN2 8-wave BM=128/BN=128)
  k_ffn1<<<dim3(64, 16), 512, 0, stream>>>(NV, W1t, H, b1);
  k_ffn2<<<dim3(4, 128), 512, 0, stream>>>(H, W2t, out, b2);
}

// Round 23
// 323.610 us; speedup vs baseline: 1.0761x; 1.0053x over previous
//
#include <hip/hip_runtime.h>
#include <stdint.h>

typedef __attribute__((ext_vector_type(8))) short bf16x8;
typedef __attribute__((ext_vector_type(8))) _Float16 f16x8;
typedef __attribute__((ext_vector_type(4))) float f32x4;
typedef __attribute__((ext_vector_type(4))) unsigned short us4;
typedef unsigned short u16;

#define DEVI static __device__ __forceinline__

#define Bb 4
#define Tt 4096
#define Cch 512
#define DFFd 2048
#define Mrows (Bb*Tt)
#define TRI 8650752ull   // u16 elements per packed causal pane = PANE(32)

DEVI u16 f2bf(float f){
  union{float f;unsigned u;} v; v.f = f;
  unsigned r = v.u + 0x7FFFu + ((v.u >> 16) & 1u);
  return (u16)(r >> 16);
}
DEVI u16 f2h(float f){
  union{_Float16 h; u16 u;} v; v.h = (_Float16)f; return v.u;
}
DEVI float h2f(u16 h){
  union{u16 u; _Float16 h;} v; v.u = h; return (float)v.h;
}
// packed-triangular pane offset (u16 elements): sum_{j<q}(j+1)*128*128
DEVI size_t PANE(int q){ return (size_t)8192 * (size_t)(q*(q+1)); }

DEVI void gload16(const void* g, void* l){
  __builtin_amdgcn_global_load_lds((const __attribute__((address_space(1))) unsigned int*)g,
                                   (__attribute__((address_space(3))) unsigned int*)l, 16, 0, 0);
}

// Bank-conflict-free swizzle (both-sides involution), verified round 16 (conflicts -> 0):
#define RDSWZ(l15, l4) (((l4)*16) ^ ((((l15) >> 1) & 3) << 4))
#define SRCSWZ(lane) ((((lane) & 3)*8) ^ ((((lane) >> 3) & 3) << 3))

// ---- 8-wave stagers (512-thread kernels) ----
DEVI void stage256x64_w8(const u16* __restrict__ base, int ld, char* lds, int w, int lane){
  #pragma unroll
  for(int i = 0; i < 4; i++){
    int s = i & 1;
    int chunk = w + (i >> 1)*8;              // 0..15
    int row = chunk*16 + (lane >> 2);
    int col = s*32 + SRCSWZ(lane);
    gload16(base + (size_t)row * ld + col, lds + s*16384 + chunk*1024 + lane*16);
  }
}
DEVI void stage128x64_w8(const u16* __restrict__ base, int ld, char* lds, int w, int lane){
  #pragma unroll
  for(int i = 0; i < 2; i++){
    int s = i;
    int row = w*16 + (lane >> 2);
    int col = s*32 + SRCSWZ(lane);
    gload16(base + (size_t)row * ld + col, lds + s*8192 + w*1024 + lane*16);
  }
}

// ---------------- cast f32 -> f16 ----------------
__global__ void k_cast_f16(const float* __restrict__ in, u16* __restrict__ out, int n){
  int i = (blockIdx.x * blockDim.x + threadIdx.x) * 4;
  if(i < n){
    float4 f = *(const float4*)(in + i);
    us4 o; o.x = f2h(f.x); o.y = f2h(f.y); o.z = f2h(f.z); o.w = f2h(f.w);
    *(us4*)(out + i) = o;
  }
}

// ------------- transpose-cast f32 -> f16 -------------
__global__ void k_transpose_f32_f16(const float* __restrict__ in, u16* __restrict__ out,
                                    int inStride, int outStride){
  __shared__ float tile[32][33];
  int c0 = blockIdx.x * 32, r0 = blockIdx.y * 32;
  int tx = threadIdx.x, ty = threadIdx.y; // (32,8)
  #pragma unroll
  for(int j = 0; j < 4; j++)
    tile[ty + 8*j][tx] = in[(size_t)(r0 + ty + 8*j) * inStride + c0 + tx];
  __syncthreads();
  #pragma unroll
  for(int j = 0; j < 4; j++)
    out[(size_t)(c0 + ty + 8*j) * outStride + r0 + tx] = f2h(tile[tx][ty + 8*j]);
}

// ------------- transpose-cast f32 -> bf16 -------------
__global__ void k_transpose_f32_bf16(const float* __restrict__ in, u16* __restrict__ out,
                                     int inStride, int outStride){
  __shared__ float tile[32][33];
  int c0 = blockIdx.x * 32, r0 = blockIdx.y * 32;
  int tx = threadIdx.x, ty = threadIdx.y;
  #pragma unroll
  for(int j = 0; j < 4; j++)
    tile[ty + 8*j][tx] = in[(size_t)(r0 + ty + 8*j) * inStride + c0 + tx];
  __syncthreads();
  #pragma unroll
  for(int j = 0; j < 4; j++)
    out[(size_t)(c0 + ty + 8*j) * outStride + r0 + tx] = f2bf(tile[tx][ty + 8*j]);
}

// ---------------- f16 GEMM core, BM=256 BN=128 BK=64, 512 threads ----------------
DEVI void core_f16_256(const u16* __restrict__ A, const u16* __restrict__ B,
                       int lda, int ldb, int K, u16* As, u16* Bs, f32x4 (&acc)[4][4]){
  const int t = threadIdx.x;
  const int lane = t & 63, w = t >> 6;     // w 0..7
  const int l15 = lane & 15, l4 = lane >> 4;
  const int wr = (w >> 1) * 64, wc = (w & 1) * 64;
  const int ro = RDSWZ(l15, l4);
  for(int kt = 0; kt < K; kt += 64){
    __syncthreads();
    stage256x64_w8(A + kt, lda, (char*)As, w, lane);
    stage128x64_w8(B + kt, ldb, (char*)Bs, w, lane);
    __syncthreads();
    f16x8 af[2][4], bfr[2][4];
    #pragma unroll
    for(int s = 0; s < 2; s++){
      #pragma unroll
      for(int mi = 0; mi < 4; mi++)
        af[s][mi] = *(const f16x8*)((const char*)As + s*16384 + (wr + mi*16 + l15)*64 + ro);
      #pragma unroll
      for(int ni = 0; ni < 4; ni++)
        bfr[s][ni] = *(const f16x8*)((const char*)Bs + s*8192 + (wc + ni*16 + l15)*64 + ro);
    }
    #pragma unroll
    for(int s = 0; s < 2; s++)
      #pragma unroll
      for(int mi = 0; mi < 4; mi++)
        #pragma unroll
        for(int ni = 0; ni < 4; ni++)
          acc[mi][ni] = __builtin_amdgcn_mfma_f32_16x16x32_f16(af[s][mi], bfr[s][ni], acc[mi][ni], 0, 0, 0);
  }
}

// ---------------- bf16 GEMM core, BM=256 BN=128 BK=64, 512 threads ----------------
DEVI void core_bf16_256(const u16* __restrict__ A, const u16* __restrict__ B,
                        int lda, int ldb, int K, u16* As, u16* Bs, f32x4 (&acc)[4][4]){
  const int t = threadIdx.x;
  const int lane = t & 63, w = t >> 6;
  const int l15 = lane & 15, l4 = lane >> 4;
  const int wr = (w >> 1) * 64, wc = (w & 1) * 64;
  const int ro = RDSWZ(l15, l4);
  for(int kt = 0; kt < K; kt += 64){
    __syncthreads();
    stage256x64_w8(A + kt, lda, (char*)As, w, lane);
    stage128x64_w8(B + kt, ldb, (char*)Bs, w, lane);
    __syncthreads();
    bf16x8 af[2][4], bfr[2][4];
    #pragma unroll
    for(int s = 0; s < 2; s++){
      #pragma unroll
      for(int mi = 0; mi < 4; mi++)
        af[s][mi] = *(const bf16x8*)((const char*)As + s*16384 + (wr + mi*16 + l15)*64 + ro);
      #pragma unroll
      for(int ni = 0; ni < 4; ni++)
        bfr[s][ni] = *(const bf16x8*)((const char*)Bs + s*8192 + (wc + ni*16 + l15)*64 + ro);
    }
    #pragma unroll
    for(int s = 0; s < 2; s++)
      #pragma unroll
      for(int mi = 0; mi < 4; mi++)
        #pragma unroll
        for(int ni = 0; ni < 4; ni++)
          acc[mi][ni] = __builtin_amdgcn_mfma_f32_16x16x32_bf16(af[s][mi], bfr[s][ni], acc[mi][ni], 0, 0, 0);
  }
}

// ---------------- fused QKV projection (f16, BM=256): cols<1024 -> QK, cols>=1024 -> blocked Vg ----------------
__global__ __launch_bounds__(512) void k_qkv(const u16* __restrict__ Xf,
                                             const u16* __restrict__ Wt,
                                             u16* __restrict__ QK,
                                             u16* __restrict__ Vg){
  __shared__ u16 As[16384], Bs[8192];
  const int bm = blockIdx.x * 256, bn = blockIdx.y * 128;
  f32x4 acc[4][4] = {};
  core_f16_256(Xf + (size_t)bm*512, Wt + (size_t)bn*512, 512, 512, 512, As, Bs, acc);
  const int t = threadIdx.x, lane = t & 63, w = t >> 6;
  const int l15 = lane & 15, l4 = lane >> 4;
  const int wr = (w >> 1) * 64, wc = (w & 1) * 64;
  #pragma unroll
  for(int mi = 0; mi < 4; mi++)
    #pragma unroll
    for(int ni = 0; ni < 4; ni++){
      int col = bn + wc + ni*16 + l15;
      #pragma unroll
      for(int r = 0; r < 4; r++){
        int row = bm + wr + mi*16 + l4*4 + r;
        u16 h = f2h(acc[mi][ni][r]);
        if(col < 1024){
          QK[(size_t)row * 1024 + col] = h;
        } else {
          int c = col - 1024;
          int b = row >> 12, tq = row & 4095;
          Vg[(size_t)b*Cch*Tt + ((size_t)(tq >> 5) * 512 + c) * 32 + (tq & 31)] = h;
        }
      }
    }
}

// ---------------- causal score GEMM (BM=128, BN=128, 8 waves): grid (32,32,nb); qt descending ----------------
__global__ __launch_bounds__(512) void k_score(const u16* __restrict__ QK, int b0,
                                               u16* __restrict__ Sp){
  const int kt = blockIdx.x, qt = 31 - blockIdx.y;
  if(kt > qt) return;
  const int zb = blockIdx.z;
  const u16* QKb = QK + (size_t)(b0 + zb) * Tt * 1024;
  u16* Spz = Sp + (size_t)zb * TRI;
  __shared__ u16 As[8192], Bs[8192];
  const u16* A = QKb + (size_t)(qt*128) * 1024;        // q rows (128)
  const u16* B = QKb + (size_t)(kt*128) * 1024 + 512;  // k rows (128)
  const int t = threadIdx.x, lane = t & 63, w = t >> 6; // w 0..7
  const int l15 = lane & 15, l4 = lane >> 4;
  const int wr = (w >> 1) * 32, wc = (w & 1) * 64;      // wave tile 32x64
  const int ro = RDSWZ(l15, l4);
  f32x4 acc[2][4] = {};
  for(int kk = 0; kk < 512; kk += 64){
    __syncthreads();
    stage128x64_w8(A + kk, 1024, (char*)As, w, lane);
    stage128x64_w8(B + kk, 1024, (char*)Bs, w, lane);
    __syncthreads();
    f16x8 af[2][2], bfr[2][4];
    #pragma unroll
    for(int s = 0; s < 2; s++){
      #pragma unroll
      for(int mi = 0; mi < 2; mi++)
        af[s][mi] = *(const f16x8*)((const char*)As + s*8192 + (wr + mi*16 + l15)*64 + ro);
      #pragma unroll
      for(int ni = 0; ni < 4; ni++)
        bfr[s][ni] = *(const f16x8*)((const char*)Bs + s*8192 + (wc + ni*16 + l15)*64 + ro);
    }
    #pragma unroll
    for(int s = 0; s < 2; s++)
      #pragma unroll
      for(int mi = 0; mi < 2; mi++)
        #pragma unroll
        for(int ni = 0; ni < 4; ni++)
          acc[mi][ni] = __builtin_amdgcn_mfma_f32_16x16x32_f16(af[s][mi], bfr[s][ni], acc[mi][ni], 0, 0, 0);
  }
  const int ldc = (qt + 1) * 128;
  u16* C = Spz + PANE(qt) + (size_t)kt*128;
  const bool diag = (kt == qt);
  #pragma unroll
  for(int mi = 0; mi < 2; mi++)
    #pragma unroll
    for(int ni = 0; ni < 4; ni++){
      int cl = wc + ni*16 + l15;
      #pragma unroll
      for(int r = 0; r < 4; r++){
        int rl = wr + mi*16 + l4*4 + r;
        float v = acc[mi][ni][r];
        if(diag && cl > rl) v = -__builtin_inff();
        C[(size_t)rl * ldc + cl] = f2h(v);
      }
    }
}

// ---------------- softmax: wave per row; f16 S -> normalized f16 P in place ----------------
__global__ __launch_bounds__(256) void k_softmax(u16* __restrict__ Sp){
  u16* Spz = Sp + (size_t)blockIdx.z * TRI;
  const int w = threadIdx.x >> 6, lane = threadIdx.x & 63;
  const int r = (1023 - blockIdx.x) * 4 + w;  // 0..4095, descending qt
  const int qt = r >> 7;
  const int nc = qt + 1;                      // chunks of 128 u16 (ushort2/lane)
  const int L = nc * 128;
  const size_t base = PANE(qt) + (size_t)(r & 127) * L;
  ushort2* rp = (ushort2*)(Spz + base);
  float2 v[32];
  float mx = -__builtin_inff();
  #pragma unroll
  for(int c = 0; c < 32; c++) if(c < nc){
    ushort2 h = rp[c*64 + lane];
    v[c].x = h2f(h.x); v[c].y = h2f(h.y);
    mx = fmaxf(mx, fmaxf(v[c].x, v[c].y));
  }
  #pragma unroll
  for(int s = 1; s < 64; s <<= 1) mx = fmaxf(mx, __shfl_xor(mx, s));
  float sm = 0.f;
  #pragma unroll
  for(int c = 0; c < 32; c++) if(c < nc){
    v[c].x = __expf(v[c].x - mx);
    v[c].y = __expf(v[c].y - mx);
    sm += v[c].x + v[c].y;
  }
  #pragma unroll
  for(int s = 1; s < 64; s <<= 1) sm += __shfl_xor(sm, s);
  const float inv = 1.f / sm;
  #pragma unroll
  for(int c = 0; c < 32; c++) if(c < nc){
    ushort2 o; o.x = f2h(v[c].x * inv); o.y = f2h(v[c].y * inv);
    rp[c*64 + lane] = o;
  }
}

// ---------------- PV GEMM (f16, BM=128, BN=128, BK=64, 512 thr / 8 waves, no atomics) ----------------
__global__ __launch_bounds__(512) void k_pv(const u16* __restrict__ Pp, const u16* __restrict__ Vg,
                                            u16* __restrict__ NV, int b0){
  const int nc = blockIdx.x, qt = 31 - blockIdx.y, zb = blockIdx.z;
  const int L = (qt + 1) * 128;
  __shared__ u16 As[8192], Bs[8192];
  const u16* A = Pp + (size_t)zb * TRI + PANE(qt);             // f16 P, row stride L
  const u16* Vgb = Vg + (size_t)(b0 + zb) * Cch * Tt;          // blocked [t/32][512 c][32] f16
  const int t = threadIdx.x, lane = t & 63, w = t >> 6;        // w 0..7
  const int l15 = lane & 15, l4 = lane >> 4;
  const int wr = (w >> 1) * 32, wc = (w & 1) * 64;             // wave tile 32x64
  const int ro = RDSWZ(l15, l4);
  f32x4 acc[2][4] = {};
  for(int kt = 0; kt < L; kt += 64){
    __syncthreads();
    stage128x64_w8(A + kt, L, (char*)As, w, lane);
    // B: blocked Vg, 2 subtiles of 8KB; 8 waves x 1KB each
    const size_t kvb0 = (size_t)(kt >> 5) * 16384 + nc*4096;   // u16 elems
    #pragma unroll
    for(int i = 0; i < 2; i++){
      int s = i;
      int crow = w*16 + (lane >> 2);
      int kvo = SRCSWZ(lane);
      gload16(Vgb + kvb0 + (size_t)s*16384 + (size_t)crow*32 + kvo,
              (char*)Bs + s*8192 + w*1024 + lane*16);
    }
    __syncthreads();
    f16x8 af[2][2], bfr[2][4];
    #pragma unroll
    for(int s = 0; s < 2; s++){
      #pragma unroll
      for(int mi = 0; mi < 2; mi++)
        af[s][mi] = *(const f16x8*)((const char*)As + s*8192 + (wr + mi*16 + l15)*64 + ro);
      #pragma unroll
      for(int ni = 0; ni < 4; ni++)
        bfr[s][ni] = *(const f16x8*)((const char*)Bs + s*8192 + (wc + ni*16 + l15)*64 + ro);
    }
    #pragma unroll
    for(int s = 0; s < 2; s++)
      #pragma unroll
      for(int mi = 0; mi < 2; mi++)
        #pragma unroll
        for(int ni = 0; ni < 4; ni++)
          acc[mi][ni] = __builtin_amdgcn_mfma_f32_16x16x32_f16(af[s][mi], bfr[s][ni], acc[mi][ni], 0, 0, 0);
  }
  u16* Cb = NV + ((size_t)(b0 + zb) * Tt + qt*128) * Cch + nc*128;
  #pragma unroll
  for(int mi = 0; mi < 2; mi++)
    #pragma unroll
    for(int ni = 0; ni < 4; ni++){
      int cl = wc + ni*16 + l15;
      #pragma unroll
      for(int r = 0; r < 4; r++){
        int rl = wr + mi*16 + l4*4 + r;
        Cb[(size_t)rl * Cch + cl] = f2bf(acc[mi][ni][r]);
      }
    }
}

// ---------------- FFN1 (BM=256): +bias, relu, bf16 out ----------------
__global__ __launch_bounds__(512) void k_ffn1(const u16* __restrict__ A,
                                              const u16* __restrict__ Bt,
                                              u16* __restrict__ Hout,
                                              const float* __restrict__ bias){
  __shared__ u16 As[16384], Bs[8192];
  const int bm = blockIdx.x * 256, bn = blockIdx.y * 128;
  f32x4 acc[4][4] = {};
  core_bf16_256(A + (size_t)bm*512, Bt + (size_t)bn*512, 512, 512, 512, As, Bs, acc);
  const int t = threadIdx.x, lane = t & 63, w = t >> 6;
  const int l15 = lane & 15, l4 = lane >> 4;
  const int wr = (w >> 1) * 64, wc = (w & 1) * 64;
  #pragma unroll
  for(int mi = 0; mi < 4; mi++)
    #pragma unroll
    for(int ni = 0; ni < 4; ni++){
      int col = bn + wc + ni*16 + l15;
      float bv = bias[col];
      #pragma unroll
      for(int r = 0; r < 4; r++){
        int row = bm + wr + mi*16 + l4*4 + r;
        float v = acc[mi][ni][r] + bv;
        v = v > 0.f ? v : 0.f;
        Hout[(size_t)row * DFFd + col] = f2bf(v);
      }
    }
}

// ---------------- FFN2 (BM=128, BN=128, BK=64, 512 thr / 8 waves): +bias, f32 direct store ----------------
__global__ __launch_bounds__(512) void k_ffn2(const u16* __restrict__ A,
                                              const u16* __restrict__ Bt,
                                              float* __restrict__ out,
                                              const float* __restrict__ bias){
  __shared__ u16 As[8192], Bs[8192];
  const int bn = blockIdx.x * 128, bm = blockIdx.y * 128;
  const int t = threadIdx.x, lane = t & 63, w = t >> 6;        // w 0..7
  const int l15 = lane & 15, l4 = lane >> 4;
  const int wr = (w >> 1) * 32, wc = (w & 1) * 64;             // wave tile 32x64
  const int ro = RDSWZ(l15, l4);
  const u16* Ap = A + (size_t)bm*2048;
  const u16* Bp = Bt + (size_t)bn*2048;
  f32x4 acc[2][4] = {};
  for(int kt = 0; kt < 2048; kt += 64){
    __syncthreads();
    stage128x64_w8(Ap + kt, 2048, (char*)As, w, lane);
    stage128x64_w8(Bp + kt, 2048, (char*)Bs, w, lane);
    __syncthreads();
    bf16x8 af[2][2], bfr[2][4];
    #pragma unroll
    for(int s = 0; s < 2; s++){
      #pragma unroll
      for(int mi = 0; mi < 2; mi++)
        af[s][mi] = *(const bf16x8*)((const char*)As + s*8192 + (wr + mi*16 + l15)*64 + ro);
      #pragma unroll
      for(int ni = 0; ni < 4; ni++)
        bfr[s][ni] = *(const bf16x8*)((const char*)Bs + s*8192 + (wc + ni*16 + l15)*64 + ro);
    }
    #pragma unroll
    for(int s = 0; s < 2; s++)
      #pragma unroll
      for(int mi = 0; mi < 2; mi++)
        #pragma unroll
        for(int ni = 0; ni < 4; ni++)
          acc[mi][ni] = __builtin_amdgcn_mfma_f32_16x16x32_bf16(af[s][mi], bfr[s][ni], acc[mi][ni], 0, 0, 0);
  }
  #pragma unroll
  for(int mi = 0; mi < 2; mi++)
    #pragma unroll
    for(int ni = 0; ni < 4; ni++){
      int col = bn + wc + ni*16 + l15;
      float bv = bias[col];
      #pragma unroll
      for(int r = 0; r < 4; r++){
        int row = bm + wr + mi*16 + l4*4 + r;
        out[(size_t)row * Cch + col] = acc[mi][ni][r] + bv;
      }
    }
}

// ---------------- launch ----------------
extern "C" void kernel_launch(void* const* d_in, const int* in_sizes, int n_in,
                              void* d_out, int out_size, void* d_ws, size_t ws_size,
                              hipStream_t stream){
  (void)in_sizes; (void)n_in; (void)out_size;
  const float* X  = (const float*)d_in[0];
  const float* Wq = (const float*)d_in[1];
  const float* Wk = (const float*)d_in[2];
  const float* Wv = (const float*)d_in[3];
  const float* W1 = (const float*)d_in[4];
  const float* b1 = (const float*)d_in[5];
  const float* W2 = (const float*)d_in[6];
  const float* b2 = (const float*)d_in[7];
  float* out = (float*)d_out;

  const size_t MB = 1024ull*1024ull;
  const size_t PANE_B = (size_t)TRI * 2;   // 17,301,504 B
  char* ws = (char*)d_ws;

  int nb = 1;
  if(ws_size >= 4*PANE_B + 71*MB) nb = 4;
  else if(ws_size >= 2*PANE_B + 71*MB) nb = 2;

  u16*   Sp = (u16*)ws;
  u16*   Xf = (u16*)ws;
  u16*   H  = (u16*)ws;
  size_t off = (size_t)nb * PANE_B;
  u16*   QK   = (u16*)(ws + off);  off += 32*MB;
  u16*   Vg   = (u16*)(ws + off);  off += 16*MB;
  u16*   NV   = (u16*)(ws + off);  off += 16*MB;
  u16*   Wt   = (u16*)(ws + off);  off += 2*MB;   // [1536][512] f16 (1.5M used)
  u16*   W1t  = (u16*)(ws + off);  off += 2*MB;
  u16*   W2t  = (u16*)(ws + off);

  dim3 tb(32, 8);

  // 1. cast X -> f16
  k_cast_f16<<<Mrows*Cch/4/256, 256, 0, stream>>>(X, Xf, Mrows*Cch);

  // 2. weight transposes: Wq/Wk/Wv -> f16 Wt rows; W1/W2 -> bf16
  k_transpose_f32_f16<<<dim3(16,16), tb, 0, stream>>>(Wq, Wt,            512, 512);
  k_transpose_f32_f16<<<dim3(16,16), tb, 0, stream>>>(Wk, Wt +  512*512, 512, 512);
  k_transpose_f32_f16<<<dim3(16,16), tb, 0, stream>>>(Wv, Wt + 1024*512, 512, 512);
  k_transpose_f32_bf16<<<dim3(64,16), tb, 0, stream>>>(W1, W1t, 2048, 512);
  k_transpose_f32_bf16<<<dim3(16,64), tb, 0, stream>>>(W2, W2t, 512, 2048);

  // 3. fused QKV projection (f16, BM=256)
  k_qkv<<<dim3(64, 12), 512, 0, stream>>>(Xf, Wt, QK, Vg);

  // 4. attention: nb batches per pass (longest-first), f16 S/P
  for(int b0 = 0; b0 < Bb; b0 += nb){
    k_score<<<dim3(32, 32, nb), 512, 0, stream>>>(QK, b0, Sp);
    k_softmax<<<dim3(1024, 1, nb), 256, 0, stream>>>(Sp);
    k_pv<<<dim3(4, 32, nb), 512, 0, stream>>>(Sp, Vg, NV, b0);
  }

  // 5. FFN (FFN1 BM=256; FFN2 8-wave BM=128/BN=128)
  k_ffn1<<<dim3(64, 16), 512, 0, stream>>>(NV, W1t, H, b1);
  k_ffn2<<<dim3(4, 128), 512, 0, stream>>>(H, W2t, out, b2);
}